// Round 4
// baseline (4223.008 us; speedup 1.0000x reference)
//
#include <hip/hip_runtime.h>
#include <stdint.h>
#include <math.h>

// LSTM B=256,T=1024,I=128,H=256,O=1. Persistent kernel, 64 WGs x 512.
// Each WG serves TWO batch-groups (A: bb=pid, B: bb=pid+8) in staggered phases:
// while one group's h-publish is in flight through the Infinity Cache, the WG
// computes the other group's entire phase. Group = 8 WGs (cb=0..7), each owns
// 32 h-comps x 4 gates. Weights shared across both groups (same cb slice).
// h exchange: packed u32 (hi|lo<<16) per comp, fire-and-forget sc0 sc1 stores;
// EVERY word carries 2 tag bits (hi LSB = t&1, lo LSB = (t>>1)&1; lo recomputed
// after hi tweak so only lo-LSB noise ~2^-15 rel). Consumer spins with counted
// vmcnt(1) fast path (loads issued a phase early), vmcnt(0) retry path.

typedef __attribute__((ext_vector_type(8))) __bf16 bf16x8;
typedef __attribute__((ext_vector_type(4))) float f32x4;
typedef __attribute__((ext_vector_type(4))) unsigned int u32x4;
typedef unsigned short u16;
typedef unsigned int u32;

#define JP  32
#define TT  1024
#define HD  256
#define ID  128

__device__ __forceinline__ u16 f2bf(float f) {          // fp32 -> bf16 RNE
  u32 u = __float_as_uint(f);
  u += 0x7FFFu + ((u >> 16) & 1u);
  return (u16)(u >> 16);
}
__device__ __forceinline__ float bf2f(u16 h) { return __uint_as_float((u32)h << 16); }
__device__ __forceinline__ f32x4 mfma(bf16x8 a, bf16x8 b, f32x4 c) {
  return __builtin_amdgcn_mfma_f32_16x16x32_bf16(a, b, c, 0, 0, 0);
}
__device__ __forceinline__ float sigf(float x) {
  return __builtin_amdgcn_rcpf(1.f + __expf(-x));
}
__device__ __forceinline__ float tanhfast(float x) {
  float e = __expf(2.f * x);
  return 1.f - 2.f * __builtin_amdgcn_rcpf(e + 1.f);
}

__global__ __launch_bounds__(512, 1) void lstm_pk(
    const float* __restrict__ x, const float* __restrict__ Wih,
    const float* __restrict__ Whh, const float* __restrict__ bih,
    const float* __restrict__ bhh, const float* __restrict__ Wfc,
    const float* __restrict__ bfc, float* __restrict__ out,
    u32* __restrict__ hg)   // u32[2 parity][256 batch][256 comp] = 512KB
{
  __shared__ u16 hHi[2][16][264], hLo[2][16][264];      // [group][batch][k]
  __shared__ u16 xHI[2][2][16][136], xLO[2][2][16][136];// [group][buf][b][e]
  __shared__ float red[8][16];

  const int tid  = threadIdx.x;
  const int pid  = blockIdx.x & 7, cb = blockIdx.x >> 3;
  const int b0A  = pid * 16, b0B = (pid + 8) * 16;
  const int lane = tid & 63, wave = tid >> 6;
  const int q    = lane >> 4, bcol = lane & 15;
  const int koff = q * 8;
  const int r15  = lane & 15;
  // A-row r -> gate (r&3), comp cb*32 + wave*4 + (r>>2); D row 4q+r' -> gate r',
  // comp wave*4+q: all 4 gates of one (j,b) cell land in one lane.
  const int grow = (r15 & 3) * HD + cb * JP + wave * 4 + (r15 >> 2);
  const int jloc = wave * 4 + q;

  // ---- weights -> VGPR A-frags, hi/lo split (shared by both groups) ----
  bf16x8 ahh_h[8], ahh_l[8], aih_h[4], aih_l[4];
#pragma unroll
  for (int kk = 0; kk < 8; ++kk) {
    const float* s = Whh + (size_t)grow * HD + kk * 32 + koff;
    float4 w0 = *(const float4*)(s), w1 = *(const float4*)(s + 4);
    float w[8] = {w0.x, w0.y, w0.z, w0.w, w1.x, w1.y, w1.z, w1.w};
    union { bf16x8 v; u16 u[8]; } th, tl;
#pragma unroll
    for (int e = 0; e < 8; ++e) {
      u16 hi = f2bf(w[e]); th.u[e] = hi; tl.u[e] = f2bf(w[e] - bf2f(hi));
    }
    ahh_h[kk] = th.v; ahh_l[kk] = tl.v;
  }
#pragma unroll
  for (int kk = 0; kk < 4; ++kk) {
    const float* s = Wih + (size_t)grow * ID + kk * 32 + koff;
    float4 w0 = *(const float4*)(s), w1 = *(const float4*)(s + 4);
    float w[8] = {w0.x, w0.y, w0.z, w0.w, w1.x, w1.y, w1.z, w1.w};
    union { bf16x8 v; u16 u[8]; } th, tl;
#pragma unroll
    for (int e = 0; e < 8; ++e) {
      u16 hi = f2bf(w[e]); th.u[e] = hi; tl.u[e] = f2bf(w[e] - bf2f(hi));
    }
    aih_h[kk] = th.v; aih_l[kk] = tl.v;
  }
  float biasr[4];
#pragma unroll
  for (int r = 0; r < 4; ++r) {
    int gr = r * HD + cb * JP + jloc;
    biasr[r] = bih[gr] + bhh[gr];
  }
  float wfc = Wfc[cb * JP + jloc];
  float bf0 = bfc[0];

  const int lb = tid >> 5, lc = (tid & 31) * 8;   // staging slice: batch, comp
  const u32* ldA0 = hg +           (b0A + lb) * 256 + lc;
  const u32* ldA1 = hg + 65536 +   (b0A + lb) * 256 + lc;
  const u32* ldB0 = hg +           (b0B + lb) * 256 + lc;
  const u32* ldB1 = hg + 65536 +   (b0B + lb) * 256 + lc;
  u32* pbA0 = hg +         (b0A + bcol) * 256 + cb * JP + jloc;
  u32* pbA1 = pbA0 + 65536;
  u32* pbB0 = hg +         (b0B + bcol) * 256 + cb * JP + jloc;
  u32* pbB1 = pbB0 + 65536;
  const float* xbA = x + (size_t)(b0A + lb) * TT * ID + (tid & 31) * 4;
  const float* xbB = x + (size_t)(b0B + lb) * TT * ID + (tid & 31) * 4;

  // ---- helpers ----
  auto issue2 = [&](u32x4& g0, u32x4& g1, const u32* ap) {
    asm volatile("global_load_dwordx4 %0, %2, off sc0 sc1\n\t"
                 "global_load_dwordx4 %1, %2, off offset:16 sc0 sc1"
                 : "=v"(g0), "=v"(g1) : "v"(ap));
  };
  auto loadx = [&](f32x4& v, const float* ap) {
    asm volatile("global_load_dwordx4 %0, %1, off" : "=v"(v) : "v"(ap));
  };
  auto pubst = [&](u32* ap, u32 w) {
    asm volatile("global_store_dword %0, %1, off sc0 sc1" :: "v"(ap), "v"(w) : "memory");
  };
  auto xproj = [&](int g, int buf, f32x4& a0, f32x4& a1, f32x4& a2) {
#pragma unroll
    for (int kk = 0; kk < 4; ++kk) {
      bf16x8 bh = *(const bf16x8*)&xHI[g][buf][bcol][kk * 32 + koff];
      bf16x8 bl = *(const bf16x8*)&xLO[g][buf][bcol][kk * 32 + koff];
      a0 = mfma(aih_h[kk], bh, a0);
      a1 = mfma(aih_h[kk], bl, a1);
      a2 = mfma(aih_l[kk], bh, a2);
    }
  };
  auto hproj = [&](int g, f32x4& a0, f32x4& a1, f32x4& a2) {
#pragma unroll
    for (int kk = 0; kk < 8; ++kk) {
      bf16x8 bh = *(const bf16x8*)&hHi[g][bcol][kk * 32 + koff];
      bf16x8 bl = *(const bf16x8*)&hLo[g][bcol][kk * 32 + koff];
      a0 = mfma(ahh_h[kk], bh, a0);
      a1 = mfma(ahh_h[kk], bl, a1);
      a2 = mfma(ahh_l[kk], bh, a2);
    }
  };
  auto stageH = [&](int g, u32x4 f0, u32x4 f1) {
    u32x4 hv = {(f0[0] & 0xFFFFu) | (f0[1] << 16), (f0[2] & 0xFFFFu) | (f0[3] << 16),
                (f1[0] & 0xFFFFu) | (f1[1] << 16), (f1[2] & 0xFFFFu) | (f1[3] << 16)};
    u32x4 lv = {(f0[0] >> 16) | (f0[1] & 0xFFFF0000u), (f0[2] >> 16) | (f0[3] & 0xFFFF0000u),
                (f1[0] >> 16) | (f1[1] & 0xFFFF0000u), (f1[2] >> 16) | (f1[3] & 0xFFFF0000u)};
    *(u32x4*)&hHi[g][lb][lc] = hv;
    *(u32x4*)&hLo[g][lb][lc] = lv;
  };
  auto xstage = [&](int g, int buf, f32x4 v) {
    int bi = tid >> 5, e4 = (tid & 31) * 4;
#pragma unroll
    for (int qq = 0; qq < 2; ++qq) {
      float v0 = v[2 * qq], v1 = v[2 * qq + 1];
      u16 h0 = f2bf(v0), h1 = f2bf(v1);
      u16 l0 = f2bf(v0 - bf2f(h0)), l1 = f2bf(v1 - bf2f(h1));
      *(u32*)&xHI[g][buf][bi][e4 + 2 * qq] = (u32)h0 | ((u32)h1 << 16);
      *(u32*)&xLO[g][buf][bi][e4 + 2 * qq] = (u32)l0 | ((u32)l1 << 16);
    }
  };
  auto cell = [&](f32x4 a0, f32x4 a1, f32x4 a2, float& c, float& hl,
                  u32 t1, u32* pp) {
    float g0 = a0[0] + a1[0] + a2[0] + biasr[0];
    float g1 = a0[1] + a1[1] + a2[1] + biasr[1];
    float g2 = a0[2] + a1[2] + a2[2] + biasr[2];
    float g3 = a0[3] + a1[3] + a2[3] + biasr[3];
    float ig = sigf(g0), fg = sigf(g1), gg = tanhfast(g2), og = sigf(g3);
    c = fg * c + ig * gg;
    float hn = og * tanhfast(c);
    hl = hn;
    u32 hi = (f2bf(hn) & ~1u) | (t1 & 1u);
    float res = hn - bf2f((u16)hi);
    u32 lo = (f2bf(res) & ~1u) | ((t1 >> 1) & 1u);
    pubst(pp, (hi & 0xFFFFu) | (lo << 16));
  };

  // ---- prologue ----
  { // stage x(0) for both groups (plain cached loads)
    f32x4 vA = *(const f32x4*)xbA;
    f32x4 vB = *(const f32x4*)xbB;
    xstage(0, 0, vA);
    xstage(1, 0, vB);
  }
  asm volatile("s_waitcnt vmcnt(0) lgkmcnt(0)" ::: "memory");  // all prologue VMEM done
  u32x4 fA0, fA1, fB0, fB1;
  issue2(fA0, fA1, ldA0);
  __syncthreads();

  float cA = 0.f, cB = 0.f, hlA = 0.f, hlB = 0.f;
  f32x4 xvA, xvB;

  for (int t = 0; t < TT; ++t) {
    const int p = t & 1, pn = p ^ 1;
    const u32 pat  = ((u32)t & 1u) | ((((u32)t >> 1) & 1u) << 16);
    const u32 t1   = (u32)t + 1u;
    const int tn   = (t + 1 < TT) ? (t + 1) : (TT - 1);

    // ================= A phase =================
    f32x4 a0 = {0,0,0,0}, a1 = {0,0,0,0}, a2 = {0,0,0,0};
    xproj(0, p, a0, a1, a2);
    // spin h_A(t): fast path counted wait (accum operands pin x-MFMAs before wait)
    if (t == 0) asm volatile("s_waitcnt vmcnt(0)"
                             : "+v"(fA0), "+v"(fA1), "+v"(a0), "+v"(a1), "+v"(a2));
    else        asm volatile("s_waitcnt vmcnt(1)"
                             : "+v"(fA0), "+v"(fA1), "+v"(a0), "+v"(a1), "+v"(a2));
    for (;;) {
      u32 ok = 1;
#pragma unroll
      for (int w = 0; w < 4; ++w) ok &= (u32)((fA0[w] & 0x10001u) == pat);
#pragma unroll
      for (int w = 0; w < 4; ++w) ok &= (u32)((fA1[w] & 0x10001u) == pat);
      if (__all((int)ok)) break;
      __builtin_amdgcn_s_sleep(1);
      const u32* ap = p ? ldA1 : ldA0;
      asm volatile("global_load_dwordx4 %0, %2, off sc0 sc1\n\t"
                   "global_load_dwordx4 %1, %2, off offset:16 sc0 sc1\n\t"
                   "s_waitcnt vmcnt(0)"
                   : "=v"(fA0), "=v"(fA1) : "v"(ap) : "memory");
    }
    stageH(0, fA0, fA1);
    issue2(fB0, fB1, p ? ldB1 : ldB0);         // B's h(t) loads fly during rest of A
    loadx(xvA, xbA + (size_t)tn * ID);         // x_A(t+1)
    __syncthreads();                           // barrier A: hA staged
    hproj(0, a0, a1, a2);
    cell(a0, a1, a2, cA, hlA, t1, pn ? pbA1 : pbA0);
    asm volatile("s_waitcnt vmcnt(1)" : "+v"(xvA));  // xvA ready (pub may fly)
    xstage(0, pn, xvA);

    // ================= B phase =================
    f32x4 b0 = {0,0,0,0}, b1 = {0,0,0,0}, b2 = {0,0,0,0};
    xproj(1, p, b0, b1, b2);
    asm volatile("s_waitcnt vmcnt(1)"
                 : "+v"(fB0), "+v"(fB1), "+v"(b0), "+v"(b1), "+v"(b2));
    for (;;) {
      u32 ok = 1;
#pragma unroll
      for (int w = 0; w < 4; ++w) ok &= (u32)((fB0[w] & 0x10001u) == pat);
#pragma unroll
      for (int w = 0; w < 4; ++w) ok &= (u32)((fB1[w] & 0x10001u) == pat);
      if (__all((int)ok)) break;
      __builtin_amdgcn_s_sleep(1);
      const u32* ap = p ? ldB1 : ldB0;
      asm volatile("global_load_dwordx4 %0, %2, off sc0 sc1\n\t"
                   "global_load_dwordx4 %1, %2, off offset:16 sc0 sc1\n\t"
                   "s_waitcnt vmcnt(0)"
                   : "=v"(fB0), "=v"(fB1) : "v"(ap) : "memory");
    }
    stageH(1, fB0, fB1);
    issue2(fA0, fA1, pn ? ldA1 : ldA0);        // A's h(t+1) loads fly early
    loadx(xvB, xbB + (size_t)tn * ID);
    __syncthreads();                           // barrier B: hB staged
    hproj(1, b0, b1, b2);
    cell(b0, b1, b2, cB, hlB, t1, pn ? pbB1 : pbB0);
    asm volatile("s_waitcnt vmcnt(1)" : "+v"(xvB));  // xvB ready; also retires fA loads
    xstage(1, pn, xvB);
  }

  // ---- epilogue: out[b] = sum_j h_T[j,b] * Wfc[j] + bfc ----
  {
    float v = hlA * wfc;
    v += __shfl_xor(v, 16); v += __shfl_xor(v, 32);
    if (lane < 16) red[wave][lane] = v;
  }
  __syncthreads();
  if (tid < 16) {
    float s = 0.f;
#pragma unroll
    for (int w = 0; w < 8; ++w) s += red[w][tid];
    if (cb == 0) s += bf0;
    atomicAdd(&out[b0A + tid], s);
  }
  __syncthreads();
  {
    float v = hlB * wfc;
    v += __shfl_xor(v, 16); v += __shfl_xor(v, 32);
    if (lane < 16) red[wave][lane] = v;
  }
  __syncthreads();
  if (tid < 16) {
    float s = 0.f;
#pragma unroll
    for (int w = 0; w < 8; ++w) s += red[w][tid];
    if (cb == 0) s += bf0;
    atomicAdd(&out[b0B + tid], s);
  }
}

extern "C" void kernel_launch(void* const* d_in, const int* in_sizes, int n_in,
                              void* d_out, int out_size, void* d_ws, size_t ws_size,
                              hipStream_t stream) {
  const float* x   = (const float*)d_in[0];
  const float* Wih = (const float*)d_in[1];
  const float* Whh = (const float*)d_in[2];
  const float* bih = (const float*)d_in[3];
  const float* bhh = (const float*)d_in[4];
  const float* Wfc = (const float*)d_in[5];
  const float* bfc = (const float*)d_in[6];
  float* out = (float*)d_out;

  u32* hg = (u32*)d_ws;                        // [2][256][256] u32 = 512KB
  const size_t need = 2ull * 256 * 256 * sizeof(u32);

  hipMemsetAsync(d_ws, 0, need, stream);       // h(0)=0, tag bits 00 (match t=0)
  hipMemsetAsync(d_out, 0, (size_t)out_size * sizeof(float), stream);
  lstm_pk<<<64, 512, 0, stream>>>(x, Wih, Whh, bih, bhh, Wfc, bfc, out, hg);
}